// Round 4
// baseline (125.380 us; speedup 1.0000x reference)
//
#include <hip/hip_runtime.h>

#define NB   16
#define NC   3
#define NH   512
#define NW   512
#define OUTH 506
#define OUTW 506
#define RPC  6           // output rows per chunk
#define NCHUNK 85        // ceil(506/6)
#define WPB  2           // waves per block (128 threads)
#define NWAVES (NB * NC * NCHUNK)   // 4080

// -------- kernel 0: init workspace (runs every call; harness doesn't re-poison)
__global__ void ssim_init_ws(unsigned int* mn, unsigned int* mx, float* sum) {
    int i = threadIdx.x;
    if (i < NB) { mn[i] = 0x7f7fffffu; mx[i] = 0u; sum[i] = 0.0f; }
}

// -------- kernel 1: per-image min/max of pred (values >= 0 -> uint-bit order == float order)
__global__ __launch_bounds__(256) void ssim_minmax(const float* __restrict__ pred,
                                                   unsigned int* __restrict__ mn,
                                                   unsigned int* __restrict__ mx) {
    int b = blockIdx.y;
    const float4* p4 = (const float4*)(pred + (size_t)b * (NC * NH * NW));
    const int n4 = (NC * NH * NW) / 4;
    float lmin = 3.4e38f, lmax = -3.4e38f;
    for (int i = blockIdx.x * blockDim.x + threadIdx.x; i < n4; i += gridDim.x * blockDim.x) {
        float4 v = p4[i];
        lmin = fminf(lmin, fminf(fminf(v.x, v.y), fminf(v.z, v.w)));
        lmax = fmaxf(lmax, fmaxf(fmaxf(v.x, v.y), fmaxf(v.z, v.w)));
    }
    #pragma unroll
    for (int off = 32; off; off >>= 1) {
        lmin = fminf(lmin, __shfl_down(lmin, off, 64));
        lmax = fmaxf(lmax, __shfl_down(lmax, off, 64));
    }
    __shared__ float smin[4], smax[4];
    int wid = threadIdx.x >> 6, lane = threadIdx.x & 63;
    if (lane == 0) { smin[wid] = lmin; smax[wid] = lmax; }
    __syncthreads();
    if (threadIdx.x == 0) {
        float m = fminf(fminf(smin[0], smin[1]), fminf(smin[2], smin[3]));
        float M = fmaxf(fmaxf(smax[0], smax[1]), fmaxf(smax[2], smax[3]));
        atomicMin(&mn[b], __float_as_uint(m));
        atomicMax(&mx[b], __float_as_uint(M));
    }
}

// -------- kernel 2: register-resident separable sliding-window SSIM (no LDS, no shuffles)
// Each wave: one (image, channel, 6-row chunk), full 512-col width.
// Each lane: 8 output cols (c0..c0+7), tracks 14 cols of vertical running sums
// (cols c0..c0+13; 2x column load redundancy instead of cross-lane traffic).
// Rows staged in 8-col halves to keep VGPR <= 128 (4 waves/SIMD).
__global__ __launch_bounds__(128, 4) void ssim_main(const float* __restrict__ tin,
                                                    const float* __restrict__ pin,
                                                    const unsigned int* __restrict__ mn,
                                                    const unsigned int* __restrict__ mx,
                                                    float* __restrict__ sum) {
    const int wid   = blockIdx.x * WPB + (threadIdx.x >> 6);
    const int lane  = threadIdx.x & 63;
    const int imgch = wid / NCHUNK;
    const int chunk = wid - imgch * NCHUNK;
    const int b     = imgch / NC;
    const int r0    = chunk * RPC;
    const int c0    = lane * 8;

    const float* tb = tin + (size_t)imgch * (NH * NW) + (size_t)r0 * NW;
    const float* pb = pin + (size_t)imgch * (NH * NW) + (size_t)r0 * NW;

    const float dr  = __uint_as_float(mx[b]) - __uint_as_float(mn[b]);
    const float c1  = (0.01f * dr) * (0.01f * dr);
    const float c2  = (0.03f * dr) * (0.03f * dr);
    const float C1s = 2401.0f * c1;   // 49^2 * c1
    const float C2s = 2352.0f * c2;   // 48*49 * c2

    const int nrows = min(RPC, OUTH - r0);   // valid output rows this chunk
    const int kmax  = nrows + 6;             // iterations; emit at k>=6

    // clamped bases for the upper half (only lane 63 clamps; its tracked
    // cols 8..13 become garbage but feed only outputs guarded by c0+c<OUTW)
    const int cb2 = min(c0 + 8,  NW - 4);
    const int cb3 = min(c0 + 12, NW - 4);

    float st[14], sp[14], stt[14], spp[14], stp[14];
    #pragma unroll
    for (int i = 0; i < 14; ++i) { st[i]=0.f; sp[i]=0.f; stt[i]=0.f; spp[i]=0.f; stp[i]=0.f; }

    float acc = 0.f;

#define UPD(I, TV, PV, SGN) do {                                    \
        float _t = (TV), _p = (PV);                                 \
        st[I]  += SGN _t;  sp[I]  += SGN _p;                        \
        stt[I] = fmaf(SGN _t, _t, stt[I]);                          \
        spp[I] = fmaf(SGN _p, _p, spp[I]);                          \
        stp[I] = fmaf(SGN _t, _p, stp[I]);                          \
    } while (0)

#define HALF0(ROWT, ROWP, SGN) do {                                 \
        float tv[8], pv[8];                                         \
        *(float4*)&tv[0] = *(const float4*)((ROWT) + c0);           \
        *(float4*)&tv[4] = *(const float4*)((ROWT) + c0 + 4);       \
        *(float4*)&pv[0] = *(const float4*)((ROWP) + c0);           \
        *(float4*)&pv[4] = *(const float4*)((ROWP) + c0 + 4);       \
        _Pragma("unroll")                                           \
        for (int i = 0; i < 8; ++i) UPD(i, tv[i], pv[i], SGN);      \
    } while (0)

#define HALF1(ROWT, ROWP, SGN) do {                                 \
        float tv[8], pv[8];                                         \
        *(float4*)&tv[0] = *(const float4*)((ROWT) + cb2);          \
        *(float4*)&tv[4] = *(const float4*)((ROWT) + cb3);          \
        *(float4*)&pv[0] = *(const float4*)((ROWP) + cb2);          \
        *(float4*)&pv[4] = *(const float4*)((ROWP) + cb3);          \
        _Pragma("unroll")                                           \
        for (int i = 0; i < 6; ++i) UPD(8 + i, tv[i], pv[i], SGN);  \
    } while (0)

#define SSIMADD(C) do {                                             \
        if (c0 + (C) < OUTW) {                                      \
            float p12 = S1 * S2;                                    \
            float q1  = S1 * S1, q2 = S2 * S2;                      \
            float A1  = fmaf(2.f, p12, C1s);                        \
            float B1  = q1 + q2 + C1s;                              \
            float mtp = fmaf(49.f, S5, -p12);                       \
            float A2  = fmaf(2.f, mtp, C2s);                        \
            float mtt = fmaf(49.f, S3, -q1);                        \
            float mpp = fmaf(49.f, S4, -q2);                        \
            float B2  = mtt + mpp + C2s;                            \
            acc += __fdividef(A1 * A2, B1 * B2);                    \
        }                                                           \
    } while (0)

    for (int k = 0; k < kmax; ++k) {
        const float* trow = tb + k * NW;
        const float* prow = pb + k * NW;
        HALF0(trow, prow, +);
        HALF1(trow, prow, +);
        if (k >= 7) {
            const float* tlr = trow - 7 * NW;
            const float* plr = prow - 7 * NW;
            HALF0(tlr, plr, -);
            HALF1(tlr, plr, -);
        }
        if (k >= 6) {
            float S1 = st[0]+st[1]+st[2]+st[3]+st[4]+st[5]+st[6];
            float S2 = sp[0]+sp[1]+sp[2]+sp[3]+sp[4]+sp[5]+sp[6];
            float S3 = stt[0]+stt[1]+stt[2]+stt[3]+stt[4]+stt[5]+stt[6];
            float S4 = spp[0]+spp[1]+spp[2]+spp[3]+spp[4]+spp[5]+spp[6];
            float S5 = stp[0]+stp[1]+stp[2]+stp[3]+stp[4]+stp[5]+stp[6];
            SSIMADD(0);
            #pragma unroll
            for (int c = 1; c < 8; ++c) {
                S1 += st[c+6]  - st[c-1];
                S2 += sp[c+6]  - sp[c-1];
                S3 += stt[c+6] - stt[c-1];
                S4 += spp[c+6] - spp[c-1];
                S5 += stp[c+6] - stp[c-1];
                SSIMADD(c);
            }
        }
    }

#undef SSIMADD
#undef HALF1
#undef HALF0
#undef UPD

    #pragma unroll
    for (int off = 32; off; off >>= 1) acc += __shfl_down(acc, off, 64);
    if (lane == 0) atomicAdd(&sum[b], acc);
}

// -------- kernel 3: finalize mean
__global__ void ssim_finalize(const float* __restrict__ sum, float* __restrict__ out) {
    int i = threadIdx.x;
    if (i < NB) out[i] = sum[i] / (float)(NC * OUTH * OUTW);
}

extern "C" void kernel_launch(void* const* d_in, const int* in_sizes, int n_in,
                              void* d_out, int out_size, void* d_ws, size_t ws_size,
                              hipStream_t stream) {
    const float* t = (const float*)d_in[0];   // true
    const float* p = (const float*)d_in[1];   // pred
    float* out = (float*)d_out;

    unsigned int* mn  = (unsigned int*)d_ws;
    unsigned int* mx  = mn + NB;
    float*        sum = (float*)(mx + NB);

    ssim_init_ws<<<1, 64, 0, stream>>>(mn, mx, sum);
    ssim_minmax<<<dim3(128, NB), 256, 0, stream>>>(p, mn, mx);

    // 4080 wave-tasks (16 img x 3 ch x 85 row-chunks), 2 waves per block
    ssim_main<<<dim3(NWAVES / WPB), 128, 0, stream>>>(t, p, mn, mx, sum);

    ssim_finalize<<<1, 64, 0, stream>>>(sum, out);
}

// Round 5
// 84.440 us; speedup vs baseline: 1.4848x; 1.4848x over previous
//
#include <hip/hip_runtime.h>

#define NB   16
#define NC   3
#define NH   512
#define NW   512
#define OUTH 506
#define OUTW 506
#define RPC  11          // output rows per chunk (506 = 46*11 exactly -> constant trip count)
#define NCH  46
#define WPB  4           // waves per block (256 threads)
#define NWAVES (NB * NC * NCH * 2)   // 4416 (x2 column halves)

// -------- kernel 0: init workspace (runs every call; harness doesn't re-poison)
__global__ void ssim_init_ws(unsigned int* mn, unsigned int* mx, float* sum) {
    int i = threadIdx.x;
    if (i < NB) { mn[i] = 0x7f7fffffu; mx[i] = 0u; sum[i] = 0.0f; }
}

// -------- kernel 1: per-image min/max of pred (values >= 0 -> uint-bit order == float order)
__global__ __launch_bounds__(256) void ssim_minmax(const float* __restrict__ pred,
                                                   unsigned int* __restrict__ mn,
                                                   unsigned int* __restrict__ mx) {
    int b = blockIdx.y;
    const float4* p4 = (const float4*)(pred + (size_t)b * (NC * NH * NW));
    const int n4 = (NC * NH * NW) / 4;
    float lmin = 3.4e38f, lmax = -3.4e38f;
    for (int i = blockIdx.x * blockDim.x + threadIdx.x; i < n4; i += gridDim.x * blockDim.x) {
        float4 v = p4[i];
        lmin = fminf(lmin, fminf(fminf(v.x, v.y), fminf(v.z, v.w)));
        lmax = fmaxf(lmax, fmaxf(fmaxf(v.x, v.y), fmaxf(v.z, v.w)));
    }
    #pragma unroll
    for (int off = 32; off; off >>= 1) {
        lmin = fminf(lmin, __shfl_down(lmin, off, 64));
        lmax = fmaxf(lmax, __shfl_down(lmax, off, 64));
    }
    __shared__ float smin[4], smax[4];
    int wid = threadIdx.x >> 6, lane = threadIdx.x & 63;
    if (lane == 0) { smin[wid] = lmin; smax[wid] = lmax; }
    __syncthreads();
    if (threadIdx.x == 0) {
        float m = fminf(fminf(smin[0], smin[1]), fminf(smin[2], smin[3]));
        float M = fmaxf(fmaxf(smax[0], smax[1]), fmaxf(smax[2], smax[3]));
        atomicMin(&mn[b], __float_as_uint(m));
        atomicMax(&mx[b], __float_as_uint(M));
    }
}

// -------- kernel 2: register-resident separable sliding-window SSIM (no LDS ops in hot path)
// Each wave: one (image-channel, 11-row chunk, 256-col half).
// Each lane: 4 output cols (c0..c0+3), tracks 10 cols of vertical running sums
// (cols c0..c0+9; 3x column load redundancy instead of cross-lane traffic).
// Constant trip count (17) -> full unroll -> compiler software-pipelines loads.
__global__ __launch_bounds__(256) void ssim_main(const float* __restrict__ tin,
                                                 const float* __restrict__ pin,
                                                 const unsigned int* __restrict__ mn,
                                                 const unsigned int* __restrict__ mx,
                                                 float* __restrict__ sum) {
    const int warp  = threadIdx.x >> 6;
    const int lane  = threadIdx.x & 63;
    const int wid   = blockIdx.x * WPB + warp;
    const int imgch = wid / (NCH * 2);
    const int rem   = wid - imgch * (NCH * 2);
    const int chunk = rem >> 1;
    const int half  = rem & 1;
    const int b     = imgch / NC;
    const int r0    = chunk * RPC;
    const int c0    = half * 256 + lane * 4;

    const float* tb = tin + (size_t)imgch * (NH * NW) + (size_t)r0 * NW;
    const float* pb = pin + (size_t)imgch * (NH * NW) + (size_t)r0 * NW;

    const float dr  = __uint_as_float(mx[b]) - __uint_as_float(mn[b]);
    const float c1  = (0.01f * dr) * (0.01f * dr);
    const float c2  = (0.03f * dr) * (0.03f * dr);
    const float C1s = 2401.0f * c1;   // 49^2 * c1
    const float C2s = 2352.0f * c2;   // 48*49 * c2

    // clamped float4 bases; clamps only bite for half=1 high lanes whose
    // affected tracked cols feed exclusively masked (>=OUTW) outputs
    const int cb0 = c0;                   // <= 508 = NW-4, in bounds
    const int cb1 = min(c0 + 4, NW - 4);
    const int cb2 = min(c0 + 8, NW - 4);

    float st[10], sp[10], stt[10], spp[10], stp[10];
    #pragma unroll
    for (int i = 0; i < 10; ++i) { st[i]=0.f; sp[i]=0.f; stt[i]=0.f; spp[i]=0.f; stp[i]=0.f; }

    float acc = 0.f;

#define LOAD12(DT, DP, RT, RP) do {                                 \
        *(float4*)&DT[0] = *(const float4*)((RT) + cb0);            \
        *(float4*)&DT[4] = *(const float4*)((RT) + cb1);            \
        *(float4*)&DT[8] = *(const float4*)((RT) + cb2);            \
        *(float4*)&DP[0] = *(const float4*)((RP) + cb0);            \
        *(float4*)&DP[4] = *(const float4*)((RP) + cb1);            \
        *(float4*)&DP[8] = *(const float4*)((RP) + cb2);            \
    } while (0)

#define SSIMADD(C) do {                                             \
        if (c0 + (C) < OUTW) {                                      \
            float p12 = S1 * S2;                                    \
            float q1  = S1 * S1, q2 = S2 * S2;                      \
            float A1  = fmaf(2.f, p12, C1s);                        \
            float B1  = q1 + q2 + C1s;                              \
            float mtp = fmaf(49.f, S5, -p12);                       \
            float A2  = fmaf(2.f, mtp, C2s);                        \
            float mtt = fmaf(49.f, S3, -q1);                        \
            float mpp = fmaf(49.f, S4, -q2);                        \
            float B2  = mtt + mpp + C2s;                            \
            acc += __fdividef(A1 * A2, B1 * B2);                    \
        }                                                           \
    } while (0)

    #pragma unroll
    for (int k = 0; k < RPC + 6; ++k) {
        const float* trow = tb + k * NW;
        const float* prow = pb + k * NW;
        float tv[12], pv[12];
        LOAD12(tv, pv, trow, prow);
        #pragma unroll
        for (int i = 0; i < 10; ++i) {
            float t_ = tv[i], p_ = pv[i];
            st[i] += t_; sp[i] += p_;
            stt[i] = fmaf(t_, t_, stt[i]);
            spp[i] = fmaf(p_, p_, spp[i]);
            stp[i] = fmaf(t_, p_, stp[i]);
        }
        if (k >= 7) {                      // remove leaving row (cache hit)
            float tl[12], pl[12];
            LOAD12(tl, pl, trow - 7 * NW, prow - 7 * NW);
            #pragma unroll
            for (int i = 0; i < 10; ++i) {
                float t_ = tl[i], p_ = pl[i];
                st[i] -= t_; sp[i] -= p_;
                stt[i] = fmaf(-t_, t_, stt[i]);
                spp[i] = fmaf(-p_, p_, spp[i]);
                stp[i] = fmaf(-t_, p_, stp[i]);
            }
        }
        if (k >= 6) {                      // emit output row r0 + k - 6
            float S1 = st[0]+st[1]+st[2]+st[3]+st[4]+st[5]+st[6];
            float S2 = sp[0]+sp[1]+sp[2]+sp[3]+sp[4]+sp[5]+sp[6];
            float S3 = stt[0]+stt[1]+stt[2]+stt[3]+stt[4]+stt[5]+stt[6];
            float S4 = spp[0]+spp[1]+spp[2]+spp[3]+spp[4]+spp[5]+spp[6];
            float S5 = stp[0]+stp[1]+stp[2]+stp[3]+stp[4]+stp[5]+stp[6];
            SSIMADD(0);
            #pragma unroll
            for (int c = 1; c < 4; ++c) {
                S1 += st[c+6]  - st[c-1];
                S2 += sp[c+6]  - sp[c-1];
                S3 += stt[c+6] - stt[c-1];
                S4 += spp[c+6] - spp[c-1];
                S5 += stp[c+6] - stp[c-1];
                SSIMADD(c);
            }
        }
    }

#undef SSIMADD
#undef LOAD12

    #pragma unroll
    for (int off = 32; off; off >>= 1) acc += __shfl_down(acc, off, 64);
    __shared__ float part[WPB];
    if (lane == 0) part[warp] = acc;
    __syncthreads();
    // all 4 waves of a block share the same image (92 waves per imgch, 4 | 92)
    if (threadIdx.x == 0)
        atomicAdd(&sum[b], part[0] + part[1] + part[2] + part[3]);
}

// -------- kernel 3: finalize mean
__global__ void ssim_finalize(const float* __restrict__ sum, float* __restrict__ out) {
    int i = threadIdx.x;
    if (i < NB) out[i] = sum[i] / (float)(NC * OUTH * OUTW);
}

extern "C" void kernel_launch(void* const* d_in, const int* in_sizes, int n_in,
                              void* d_out, int out_size, void* d_ws, size_t ws_size,
                              hipStream_t stream) {
    const float* t = (const float*)d_in[0];   // true
    const float* p = (const float*)d_in[1];   // pred
    float* out = (float*)d_out;

    unsigned int* mn  = (unsigned int*)d_ws;
    unsigned int* mx  = mn + NB;
    float*        sum = (float*)(mx + NB);

    ssim_init_ws<<<1, 64, 0, stream>>>(mn, mx, sum);
    ssim_minmax<<<dim3(128, NB), 256, 0, stream>>>(p, mn, mx);

    // 4416 wave-tasks (16 img x 3 ch x 46 row-chunks x 2 col-halves), 4 waves/block
    ssim_main<<<dim3(NWAVES / WPB), 256, 0, stream>>>(t, p, mn, mx, sum);

    ssim_finalize<<<1, 64, 0, stream>>>(sum, out);
}

// Round 6
// 69.262 us; speedup vs baseline: 1.8102x; 1.2191x over previous
//
#include <hip/hip_runtime.h>

#define NB   16
#define NC   3
#define NH   512
#define NW   512
#define OUTH 506
#define OUTW 506
#define NCHK 42          // 40 chunks x 12 rows + 2 chunks x 13 rows = 506
#define WPB  4           // waves per block (256 threads)
#define NTASK (NB * NC * NCHK * 2)   // 4032 -> 1008 blocks (<= 1024 resident)

// -------- kernel 0: init workspace (runs every call; harness doesn't re-poison)
__global__ void ssim_init_ws(unsigned int* mn, unsigned int* mx, float* sum) {
    int i = threadIdx.x;
    if (i < NB) { mn[i] = 0x7f7fffffu; mx[i] = 0u; sum[i] = 0.0f; }
}

// -------- kernel 1: per-image min/max of pred (values >= 0 -> uint-bit order == float order)
__global__ __launch_bounds__(256) void ssim_minmax(const float* __restrict__ pred,
                                                   unsigned int* __restrict__ mn,
                                                   unsigned int* __restrict__ mx) {
    int b = blockIdx.y;
    const float4* p4 = (const float4*)(pred + (size_t)b * (NC * NH * NW));
    const int n4 = (NC * NH * NW) / 4;
    float lmin = 3.4e38f, lmax = -3.4e38f;
    for (int i = blockIdx.x * blockDim.x + threadIdx.x; i < n4; i += gridDim.x * blockDim.x) {
        float4 v = p4[i];
        lmin = fminf(lmin, fminf(fminf(v.x, v.y), fminf(v.z, v.w)));
        lmax = fmaxf(lmax, fmaxf(fmaxf(v.x, v.y), fmaxf(v.z, v.w)));
    }
    #pragma unroll
    for (int off = 32; off; off >>= 1) {
        lmin = fminf(lmin, __shfl_down(lmin, off, 64));
        lmax = fmaxf(lmax, __shfl_down(lmax, off, 64));
    }
    __shared__ float smin[4], smax[4];
    int wid = threadIdx.x >> 6, lane = threadIdx.x & 63;
    if (lane == 0) { smin[wid] = lmin; smax[wid] = lmax; }
    __syncthreads();
    if (threadIdx.x == 0) {
        float m = fminf(fminf(smin[0], smin[1]), fminf(smin[2], smin[3]));
        float M = fmaxf(fmaxf(smax[0], smax[1]), fmaxf(smax[2], smax[3]));
        atomicMin(&mn[b], __float_as_uint(m));
        atomicMax(&mx[b], __float_as_uint(M));
    }
}

// -------- kernel 2: register-resident separable sliding-window SSIM
// Each wave: one (image-channel, 12/13-row chunk, 256-col half).
// Each lane: 4 output cols, tracks 10 cols of vertical running sums.
// 1008 blocks, VGPR<=128 -> 4 blocks/CU -> ALL blocks resident at t=0 (no tail).
__global__ __launch_bounds__(256) void ssim_main(const float* __restrict__ tin,
                                                 const float* __restrict__ pin,
                                                 const unsigned int* __restrict__ mn,
                                                 const unsigned int* __restrict__ mx,
                                                 float* __restrict__ sum) {
    const int warp  = threadIdx.x >> 6;
    const int lane  = threadIdx.x & 63;
    const int wid   = blockIdx.x * WPB + warp;
    const int imgch = wid / (NCHK * 2);
    const int rem   = wid - imgch * (NCHK * 2);
    const int chunk = rem >> 1;
    const int half  = rem & 1;
    const int b     = imgch / NC;
    const int r0    = chunk * 12 + max(0, chunk - 40);   // chunks 40,41 have 13 rows
    const bool big  = (chunk >= 40);
    const int c0    = half * 256 + lane * 4;

    const float* tb = tin + (size_t)imgch * (NH * NW) + (size_t)r0 * NW;
    const float* pb = pin + (size_t)imgch * (NH * NW) + (size_t)r0 * NW;

    const float dr  = __uint_as_float(mx[b]) - __uint_as_float(mn[b]);
    const float c1  = (0.01f * dr) * (0.01f * dr);
    const float c2  = (0.03f * dr) * (0.03f * dr);
    const float C1s = 2401.0f * c1;   // 49^2 * c1
    const float C2s = 2352.0f * c2;   // 48*49 * c2

    // clamped bases; clamps bite only for half=1 lanes 62-63 whose affected
    // tracked slots feed exclusively masked (>= OUTW) outputs
    const int cb0 = c0;                   // <= 508 = NW-4, in bounds
    const int cb1 = min(c0 + 4, NW - 4);
    const int cb2 = min(c0 + 8, NW - 2);  // float2 load (cols c0+8, c0+9)

    float st[10], sp[10], stt[10], spp[10], stp[10];
    #pragma unroll
    for (int i = 0; i < 10; ++i) { st[i]=0.f; sp[i]=0.f; stt[i]=0.f; spp[i]=0.f; stp[i]=0.f; }

    float acc = 0.f;

#define UPD1(I, T_, P_, SGN) do {                                   \
        float _t = (T_), _p = (P_);                                 \
        st[I]  += SGN _t;  sp[I]  += SGN _p;                        \
        stt[I] = fmaf(SGN _t, _t, stt[I]);                          \
        spp[I] = fmaf(SGN _p, _p, spp[I]);                          \
        stp[I] = fmaf(SGN _t, _p, stp[I]);                          \
    } while (0)

#define UPDROW(RT, RP, SGN) do {                                    \
        float4 t0 = *(const float4*)((RT) + cb0);                   \
        float4 t1 = *(const float4*)((RT) + cb1);                   \
        float2 t2 = *(const float2*)((RT) + cb2);                   \
        float4 p0 = *(const float4*)((RP) + cb0);                   \
        float4 p1 = *(const float4*)((RP) + cb1);                   \
        float2 p2 = *(const float2*)((RP) + cb2);                   \
        UPD1(0, t0.x, p0.x, SGN); UPD1(1, t0.y, p0.y, SGN);         \
        UPD1(2, t0.z, p0.z, SGN); UPD1(3, t0.w, p0.w, SGN);         \
        UPD1(4, t1.x, p1.x, SGN); UPD1(5, t1.y, p1.y, SGN);         \
        UPD1(6, t1.z, p1.z, SGN); UPD1(7, t1.w, p1.w, SGN);         \
        UPD1(8, t2.x, p2.x, SGN); UPD1(9, t2.y, p2.y, SGN);         \
    } while (0)

#define SSIMADD(C) do {                                             \
        if (c0 + (C) < OUTW) {                                      \
            float p12 = S1 * S2;                                    \
            float q1  = S1 * S1, q2 = S2 * S2;                      \
            float A1  = fmaf(2.f, p12, C1s);                        \
            float B1  = q1 + q2 + C1s;                              \
            float mtp = fmaf(49.f, S5, -p12);                       \
            float A2  = fmaf(2.f, mtp, C2s);                        \
            float mtt = fmaf(49.f, S3, -q1);                        \
            float mpp = fmaf(49.f, S4, -q2);                        \
            float B2  = mtt + mpp + C2s;                            \
            acc += __fdividef(A1 * A2, B1 * B2);                    \
        }                                                           \
    } while (0)

#define STEP(K) do {                                                \
        const float* trow = tb + (K) * NW;                          \
        const float* prow = pb + (K) * NW;                          \
        UPDROW(trow, prow, +);                                      \
        if ((K) >= 7) {                                             \
            UPDROW(trow - 7 * NW, prow - 7 * NW, -);                \
        }                                                           \
        if ((K) >= 6) {                                             \
            float S1 = st[0]+st[1]+st[2]+st[3]+st[4]+st[5]+st[6];   \
            float S2 = sp[0]+sp[1]+sp[2]+sp[3]+sp[4]+sp[5]+sp[6];   \
            float S3 = stt[0]+stt[1]+stt[2]+stt[3]+stt[4]+stt[5]+stt[6]; \
            float S4 = spp[0]+spp[1]+spp[2]+spp[3]+spp[4]+spp[5]+spp[6]; \
            float S5 = stp[0]+stp[1]+stp[2]+stp[3]+stp[4]+stp[5]+stp[6]; \
            SSIMADD(0);                                             \
            _Pragma("unroll")                                       \
            for (int c = 1; c < 4; ++c) {                           \
                S1 += st[c+6]  - st[c-1];                           \
                S2 += sp[c+6]  - sp[c-1];                           \
                S3 += stt[c+6] - stt[c-1];                          \
                S4 += spp[c+6] - spp[c-1];                          \
                S5 += stp[c+6] - stp[c-1];                          \
                SSIMADD(c);                                         \
            }                                                       \
        }                                                           \
    } while (0)

    // constant 18-iteration unrolled loop (12 output rows); the two 13-row
    // chunks run one extra guarded iteration (wave-uniform branch)
    #pragma unroll
    for (int k = 0; k < 18; ++k) { STEP(k); }
    if (big) { STEP(18); }

#undef STEP
#undef SSIMADD
#undef UPDROW
#undef UPD1

    #pragma unroll
    for (int off = 32; off; off >>= 1) acc += __shfl_down(acc, off, 64);
    __shared__ float part[WPB];
    if (lane == 0) part[warp] = acc;
    __syncthreads();
    // all 4 waves of a block share the same image (84 wids per imgch, 4 | 84)
    if (threadIdx.x == 0)
        atomicAdd(&sum[b], part[0] + part[1] + part[2] + part[3]);
}

// -------- kernel 3: finalize mean
__global__ void ssim_finalize(const float* __restrict__ sum, float* __restrict__ out) {
    int i = threadIdx.x;
    if (i < NB) out[i] = sum[i] / (float)(NC * OUTH * OUTW);
}

extern "C" void kernel_launch(void* const* d_in, const int* in_sizes, int n_in,
                              void* d_out, int out_size, void* d_ws, size_t ws_size,
                              hipStream_t stream) {
    const float* t = (const float*)d_in[0];   // true
    const float* p = (const float*)d_in[1];   // pred
    float* out = (float*)d_out;

    unsigned int* mn  = (unsigned int*)d_ws;
    unsigned int* mx  = mn + NB;
    float*        sum = (float*)(mx + NB);

    ssim_init_ws<<<1, 64, 0, stream>>>(mn, mx, sum);
    ssim_minmax<<<dim3(64, NB), 256, 0, stream>>>(p, mn, mx);

    // 4032 wave-tasks (16 img x 3 ch x 42 chunks x 2 col-halves), 4 waves/block
    ssim_main<<<dim3(NTASK / WPB), 256, 0, stream>>>(t, p, mn, mx, sum);

    ssim_finalize<<<1, 64, 0, stream>>>(sum, out);
}